// Round 3
// baseline (384.268 us; speedup 1.0000x reference)
//
#include <hip/hip_runtime.h>

#define T_STEPS 512
#define HSTRIDE 72              // shorts per LDS h-row (16B-aligned, 2-way-max conflicts = free)

typedef short short8 __attribute__((ext_vector_type(8)));
typedef float f32x4 __attribute__((ext_vector_type(4)));

__device__ __forceinline__ float ex2(float x) {
#if __has_builtin(__builtin_amdgcn_exp2f)
    return __builtin_amdgcn_exp2f(x);
#else
    return exp2f(x);
#endif
}
__device__ __forceinline__ float rcp_fast(float x) {
#if __has_builtin(__builtin_amdgcn_rcpf)
    return __builtin_amdgcn_rcpf(x);
#else
    return 1.0f / x;
#endif
}
__device__ __forceinline__ float fast_sig(float x) {
    return rcp_fast(1.0f + ex2(x * -1.442695041f));
}
__device__ __forceinline__ float fast_tanh(float x) {
    // tanh(x) = 1 - 2/(1+exp2(2x*log2e)); saturates correctly at +/-inf
    return fmaf(-2.0f, rcp_fast(1.0f + ex2(x * 2.885390082f)), 1.0f);
}
__device__ __forceinline__ unsigned short f2bf(float f) {
    union { float f; unsigned u; } v; v.f = f;
    unsigned r = v.u + 0x7fffu + ((v.u >> 16) & 1u);   // RNE
    return (unsigned short)(r >> 16);
}
__device__ __forceinline__ float bf2f(unsigned short b) {
    union { float f; unsigned u; } v; v.u = ((unsigned)b) << 16;
    return v.f;
}

// partial fc-dot over this lane's A-fragment slice, reduced over the 4 k-quads
__device__ __forceinline__ float out_dot(short8 a0, short8 a1,
                                         const float* wfc0, const float* wfc1) {
    float s = 0.f;
#pragma unroll
    for (int j = 0; j < 8; ++j) s = fmaf(bf2f((unsigned short)a0[j]), wfc0[j], s);
#pragma unroll
    for (int j = 0; j < 8; ++j) s = fmaf(bf2f((unsigned short)a1[j]), wfc1[j], s);
    s += __shfl_xor(s, 16);
    s += __shfl_xor(s, 32);
    return s;   // full 64-dot for batch row m = lane&15, on all lanes
}

// 512 threads = 8 waves = 2 waves/SIMD. Waves w and w+4 duplicate the MFMAs
// for unit-group (w&3); wave w handles C/D rows {0,1}, wave w+4 rows {2,3}.
__global__ __launch_bounds__(512, 1) void lstm_kernel(
    const float* __restrict__ x, const float* __restrict__ w_ih,
    const float* __restrict__ w_hh, const float* __restrict__ b_ih,
    const float* __restrict__ b_hh, const float* __restrict__ w_fc,
    const float* __restrict__ b_fc, float* __restrict__ out)
{
    __shared__ __align__(16) unsigned short hbuf[2][16 * HSTRIDE];

    const int tid  = threadIdx.x;
    const int w    = tid >> 6;      // wave 0..7
    const int wb   = w & 3;         // unit group: owns hidden units 16wb..16wb+15
    const int g2   = w >> 2;        // row-split: 0 -> rows {0,1}, 1 -> rows {2,3}
    const int lane = tid & 63;
    const int qq   = lane >> 4;     // k-quad / row-group
    const int c    = lane & 15;     // N-col (gate/unit) and A-row (batch)
    const int b0   = blockIdx.x * 16;

    // zero read-buffer for step 0 (h_{-1} = 0)
    for (int i = tid; i < 16 * HSTRIDE; i += 512) hbuf[0][i] = 0;

    // ---- B fragments (weights) in VGPRs: tile n = gate class, K-frag kk ----
    // B[k][ncol]: lane holds k = 32*kk + 8*qq + j, ncol = c; gate g = 64n+16wb+c
    short8 bfrag[4][2];
    float bias_n[4], wih_n[4];
#pragma unroll
    for (int n = 0; n < 4; ++n) {
        int g = 64 * n + 16 * wb + c;
        bias_n[n] = b_ih[g] + b_hh[g];
        wih_n[n]  = w_ih[g];
#pragma unroll
        for (int kk = 0; kk < 2; ++kk) {
            const float* wp = w_hh + g * 64 + 32 * kk + 8 * qq;
            float4 lo = *(const float4*)(wp);
            float4 hi = *(const float4*)(wp + 4);
            short8 f;
            f[0] = (short)f2bf(lo.x); f[1] = (short)f2bf(lo.y);
            f[2] = (short)f2bf(lo.z); f[3] = (short)f2bf(lo.w);
            f[4] = (short)f2bf(hi.x); f[5] = (short)f2bf(hi.y);
            f[6] = (short)f2bf(hi.z); f[7] = (short)f2bf(hi.w);
            bfrag[n][kk] = f;
        }
    }

    // fc weights aligned to this lane's A-fragment k-slice
    float wfc0[8], wfc1[8];
#pragma unroll
    for (int j = 0; j < 8; ++j) { wfc0[j] = w_fc[8 * qq + j]; wfc1[j] = w_fc[32 + 8 * qq + j]; }
    const float bfc = b_fc[0];

    float cs[2] = {0.f, 0.f};       // fp32 cell state, rows qq*4 + 2*g2 + rr

    const float* xrow[2];
#pragma unroll
    for (int rr = 0; rr < 2; ++rr)
        xrow[rr] = x + (size_t)(b0 + qq * 4 + 2 * g2 + rr) * T_STEPS;

    // x double-buffer: 4 timesteps per quad, this wave's 2 rows
    float xcur[8], xnxt[8];
#pragma unroll
    for (int rr = 0; rr < 2; ++rr) {
        float4 v = *(const float4*)(xrow[rr]);
        xcur[4*rr] = v.x; xcur[4*rr+1] = v.y; xcur[4*rr+2] = v.z; xcur[4*rr+3] = v.w;
    }
#pragma unroll
    for (int rr = 0; rr < 2; ++rr) {
        float4 v = *(const float4*)(xrow[rr] + 4);
        xnxt[4*rr] = v.x; xnxt[4*rr+1] = v.y; xnxt[4*rr+2] = v.z; xnxt[4*rr+3] = v.w;
    }

    __syncthreads();

    short8 sa0 = {}, sa1 = {};      // saved A-frags for rotated fc-dot

    for (int tq = 0; tq < 128; ++tq) {
#pragma unroll
        for (int dt = 0; dt < 4; ++dt) {
            const int t  = tq * 4 + dt;
            const int rb = t & 1;
            const unsigned short* hrd = hbuf[rb];

            // A-frags: A[m=c][k=32kk+8qq+j] of h_{t-1}
            short8 a0 = *(const short8*)(hrd + c * HSTRIDE + 8 * qq);
            short8 a1 = *(const short8*)(hrd + c * HSTRIDE + 32 + 8 * qq);

            if (dt == wb) { sa0 = a0; sa1 = a1; }   // rotate fc-dot ownership

            // acc init = x*w_ih + (b_ih+b_hh) for OUR rows only (rows are
            // independent in MFMA; other rows carry garbage we never read)
            f32x4 acc[4];
#pragma unroll
            for (int n = 0; n < 4; ++n) {
                float t0 = fmaf(xcur[0 * 4 + dt], wih_n[n], bias_n[n]);
                float t1 = fmaf(xcur[1 * 4 + dt], wih_n[n], bias_n[n]);
                f32x4 a;
                if (g2 == 0) { a[0] = t0;  a[1] = t1;  a[2] = 0.f; a[3] = 0.f; }
                else         { a[0] = 0.f; a[1] = 0.f; a[2] = t0;  a[3] = t1;  }
                acc[n] = __builtin_amdgcn_mfma_f32_16x16x32_bf16(a0, bfrag[n][0], a, 0, 0, 0);
                acc[n] = __builtin_amdgcn_mfma_f32_16x16x32_bf16(a1, bfrag[n][1], acc[n], 0, 0, 0);
            }

            // activations + state update; this wave owns units u = 16wb+c,
            // rows qq*4 + 2*g2 + rr
            unsigned short* hwr = hbuf[rb ^ 1];
#pragma unroll
            for (int rr = 0; rr < 2; ++rr) {
                float v0, v1, v2, v3;
                if (g2 == 0) { v0 = acc[0][rr];     v1 = acc[1][rr];
                               v2 = acc[2][rr];     v3 = acc[3][rr]; }
                else         { v0 = acc[0][2 + rr]; v1 = acc[1][2 + rr];
                               v2 = acc[2][2 + rr]; v3 = acc[3][2 + rr]; }
                float gi = fast_sig(v0);
                float gf = fast_sig(v1);
                float gg = fast_tanh(v2);
                float go = fast_sig(v3);
                cs[rr] = fmaf(gf, cs[rr], gi * gg);
                float h = go * fast_tanh(cs[rr]);
                hwr[(qq * 4 + 2 * g2 + rr) * HSTRIDE + 16 * wb + c] = f2bf(h);
            }
            __syncthreads();
        }

        // rotated fc-dot: wave group g2 handles quads of matching parity;
        // saved frag is A of step st = tq*4+wb, i.e. h_{st-1} -> out col st-1
        if ((tq & 1) == g2) {
            int st = tq * 4 + wb;
            if (st > 0) {
                float s = out_dot(sa0, sa1, wfc0, wfc1);
                if (lane < 16) out[(size_t)(b0 + c) * T_STEPS + (st - 1)] = s + bfc;
            }
        }

        // rotate x buffers, prefetch quad tq+2
#pragma unroll
        for (int i = 0; i < 8; ++i) xcur[i] = xnxt[i];
        if (tq < 126) {
            const int t4n = (tq + 2) * 4;
#pragma unroll
            for (int rr = 0; rr < 2; ++rr) {
                float4 v = *(const float4*)(xrow[rr] + t4n);
                xnxt[4*rr] = v.x; xnxt[4*rr+1] = v.y; xnxt[4*rr+2] = v.z; xnxt[4*rr+3] = v.w;
            }
        }
    }

    // final output column: h_511 lives in hbuf[0] (step 511 wrote rb^1 = 0)
    if (w == 7) {
        const unsigned short* hrd = hbuf[0];
        short8 a0 = *(const short8*)(hrd + c * HSTRIDE + 8 * qq);
        short8 a1 = *(const short8*)(hrd + c * HSTRIDE + 32 + 8 * qq);
        float s = out_dot(a0, a1, wfc0, wfc1);
        if (lane < 16) out[(size_t)(b0 + c) * T_STEPS + (T_STEPS - 1)] = s + bfc;
    }
}

extern "C" void kernel_launch(void* const* d_in, const int* in_sizes, int n_in,
                              void* d_out, int out_size, void* d_ws, size_t ws_size,
                              hipStream_t stream) {
    const float* x    = (const float*)d_in[0];
    const float* w_ih = (const float*)d_in[1];
    const float* w_hh = (const float*)d_in[2];
    const float* b_ih = (const float*)d_in[3];
    const float* b_hh = (const float*)d_in[4];
    const float* w_fc = (const float*)d_in[5];
    const float* b_fc = (const float*)d_in[6];
    float* out = (float*)d_out;
    hipLaunchKernelGGL(lstm_kernel, dim3(128), dim3(512), 0, stream,
                       x, w_ih, w_hh, b_ih, b_hh, w_fc, b_fc, out);
}

// Round 4
// 343.647 us; speedup vs baseline: 1.1182x; 1.1182x over previous
//
#include <hip/hip_runtime.h>

#define T_STEPS 512
#define HSTRIDE 72     // shorts per LDS h-row (16B-aligned; 2-way max conflicts = free)
#define XSTRIDE 520    // _Float16 per x-row (pad -> 2-way max on quad reads)
#define OSTRIDE 513    // floats per out-row (pad -> conflict-free column writes)

typedef short short8 __attribute__((ext_vector_type(8)));
typedef float f32x4 __attribute__((ext_vector_type(4)));
typedef _Float16 half4 __attribute__((ext_vector_type(4)));

__device__ __forceinline__ float ex2(float x) {
#if __has_builtin(__builtin_amdgcn_exp2f)
    return __builtin_amdgcn_exp2f(x);
#else
    return exp2f(x);
#endif
}
__device__ __forceinline__ float rcp_fast(float x) {
#if __has_builtin(__builtin_amdgcn_rcpf)
    return __builtin_amdgcn_rcpf(x);
#else
    return 1.0f / x;
#endif
}
__device__ __forceinline__ float fast_sig(float x) {
    return rcp_fast(1.0f + ex2(x * -1.442695041f));
}
__device__ __forceinline__ float fast_tanh(float x) {
    // tanh(x) = 1 - 2/(1+exp2(2x*log2e)); saturates correctly at +/-inf
    return fmaf(-2.0f, rcp_fast(1.0f + ex2(x * 2.885390082f)), 1.0f);
}
__device__ __forceinline__ unsigned short f2bf(float f) {
    union { float f; unsigned u; } v; v.f = f;
    unsigned r = v.u + 0x7fffu + ((v.u >> 16) & 1u);   // RNE
    return (unsigned short)(r >> 16);
}
__device__ __forceinline__ float bf2f(unsigned short b) {
    union { float f; unsigned u; } v; v.u = ((unsigned)b) << 16;
    return v.f;
}

// partial fc-dot over this lane's A-fragment slice, reduced over the 4 k-quads
__device__ __forceinline__ float out_dot(short8 a0, short8 a1,
                                         const float* wfc0, const float* wfc1) {
    float s = 0.f;
#pragma unroll
    for (int j = 0; j < 8; ++j) s = fmaf(bf2f((unsigned short)a0[j]), wfc0[j], s);
#pragma unroll
    for (int j = 0; j < 8; ++j) s = fmaf(bf2f((unsigned short)a1[j]), wfc1[j], s);
    s += __shfl_xor(s, 16);
    s += __shfl_xor(s, 32);
    return s;   // full 64-dot for batch row m = lane&15, on all lanes
}

// 256 thr = 4 waves. Wave w owns hidden units 16w..16w+15 (4 gate tiles).
// The 512-step loop touches ONLY LDS: x pre-staged (fp16), out accumulated
// in LDS, bulk-stored at the end -> per-step __syncthreads drains lgkm only.
__global__ __launch_bounds__(256, 1) void lstm_kernel(
    const float* __restrict__ x, const float* __restrict__ w_ih,
    const float* __restrict__ w_hh, const float* __restrict__ b_ih,
    const float* __restrict__ b_hh, const float* __restrict__ w_fc,
    const float* __restrict__ b_fc, float* __restrict__ out)
{
    __shared__ __align__(16) unsigned short hbuf[2][16 * HSTRIDE];  // 4.6 KB
    __shared__ __align__(16) _Float16 xls[16 * XSTRIDE];            // 16.6 KB
    __shared__ __align__(16) float ols[16 * OSTRIDE];               // 32.8 KB

    const int tid  = threadIdx.x;
    const int w    = tid >> 6;      // wave 0..3
    const int lane = tid & 63;
    const int qq   = lane >> 4;     // k-quad / row-group
    const int c    = lane & 15;     // N-col (gate/unit) and A-row (batch)
    const int b0   = blockIdx.x * 16;

    // ---- stage x: global -> LDS (fp16), coalesced float4 reads ----
    for (int i = tid; i < 2048; i += 256) {          // 16 rows x 128 float4
        int b  = i >> 7;
        int t4 = i & 127;
        float4 v = *(const float4*)(x + (size_t)(b0 + b) * T_STEPS + t4 * 4);
        half4 hv;
        hv[0] = (_Float16)v.x; hv[1] = (_Float16)v.y;
        hv[2] = (_Float16)v.z; hv[3] = (_Float16)v.w;
        *(half4*)(&xls[b * XSTRIDE + t4 * 4]) = hv;
    }
    // zero read-buffer for step 0 (h_{-1} = 0)
    for (int i = tid; i < 16 * HSTRIDE; i += 256) hbuf[0][i] = 0;

    // ---- B fragments (weights) in VGPRs: tile n = gate class, K-frag kk ----
    // B[k][ncol]: lane holds k = 32*kk + 8*qq + j, ncol = c; gate g = 64n+16w+c
    short8 bfrag[4][2];
    float bias_n[4], wih_n[4];
#pragma unroll
    for (int n = 0; n < 4; ++n) {
        int g = 64 * n + 16 * w + c;
        bias_n[n] = b_ih[g] + b_hh[g];
        wih_n[n]  = w_ih[g];
#pragma unroll
        for (int kk = 0; kk < 2; ++kk) {
            const float* wp = w_hh + g * 64 + 32 * kk + 8 * qq;
            float4 lo = *(const float4*)(wp);
            float4 hi = *(const float4*)(wp + 4);
            short8 f;
            f[0] = (short)f2bf(lo.x); f[1] = (short)f2bf(lo.y);
            f[2] = (short)f2bf(lo.z); f[3] = (short)f2bf(lo.w);
            f[4] = (short)f2bf(hi.x); f[5] = (short)f2bf(hi.y);
            f[6] = (short)f2bf(hi.z); f[7] = (short)f2bf(hi.w);
            bfrag[n][kk] = f;
        }
    }

    // fc weights aligned to this lane's A-fragment k-slice
    float wfc0[8], wfc1[8];
#pragma unroll
    for (int j = 0; j < 8; ++j) { wfc0[j] = w_fc[8 * qq + j]; wfc1[j] = w_fc[32 + 8 * qq + j]; }
    const float bfc = b_fc[0];

    float cs[4] = {0.f, 0.f, 0.f, 0.f};   // fp32 cell state, rows qq*4+r

    __syncthreads();

    short8 sa0 = {}, sa1 = {};     // saved A-frags for rotated fc-dot

    for (int tq = 0; tq < 128; ++tq) {
        // this quad's x values from LDS (broadcast across c-lanes; lgkm only)
        float xq[4][4];            // [row r][dt]
#pragma unroll
        for (int r = 0; r < 4; ++r) {
            half4 hx = *(const half4*)(&xls[(4 * qq + r) * XSTRIDE + tq * 4]);
            xq[r][0] = (float)hx[0]; xq[r][1] = (float)hx[1];
            xq[r][2] = (float)hx[2]; xq[r][3] = (float)hx[3];
        }

#pragma unroll
        for (int dt = 0; dt < 4; ++dt) {
            const int t  = tq * 4 + dt;
            const int rb = t & 1;
            const unsigned short* hrd = hbuf[rb];

            // A-frags: A[m=c][k=32kk+8qq+j] of h_{t-1}
            short8 a0 = *(const short8*)(hrd + c * HSTRIDE + 8 * qq);
            short8 a1 = *(const short8*)(hrd + c * HSTRIDE + 32 + 8 * qq);

            if (dt == w) { sa0 = a0; sa1 = a1; }   // rotate fc-dot ownership

            // acc init = x*w_ih + (b_ih+b_hh); C/D row = qq*4+r, col = c
            f32x4 acc[4];
#pragma unroll
            for (int n = 0; n < 4; ++n) {
                f32x4 a;
                a[0] = fmaf(xq[0][dt], wih_n[n], bias_n[n]);
                a[1] = fmaf(xq[1][dt], wih_n[n], bias_n[n]);
                a[2] = fmaf(xq[2][dt], wih_n[n], bias_n[n]);
                a[3] = fmaf(xq[3][dt], wih_n[n], bias_n[n]);
                acc[n] = __builtin_amdgcn_mfma_f32_16x16x32_bf16(a0, bfrag[n][0], a, 0, 0, 0);
                acc[n] = __builtin_amdgcn_mfma_f32_16x16x32_bf16(a1, bfrag[n][1], acc[n], 0, 0, 0);
            }

            // activations + state update; this wave owns units u = 16w+c
            unsigned short* hwr = hbuf[rb ^ 1];
#pragma unroll
            for (int r = 0; r < 4; ++r) {
                float gi = fast_sig(acc[0][r]);
                float gf = fast_sig(acc[1][r]);
                float gg = fast_tanh(acc[2][r]);
                float go = fast_sig(acc[3][r]);
                cs[r] = fmaf(gf, cs[r], gi * gg);
                float h = go * fast_tanh(cs[r]);
                hwr[(qq * 4 + r) * HSTRIDE + 16 * w + c] = f2bf(h);
            }
            __syncthreads();
        }

        // rotated fc-dot: saved frag is A of step st = tq*4+w = h_{st-1};
        // result goes to the LDS out buffer (NO global store in the loop)
        {
            int st = tq * 4 + w;
            if (st > 0) {
                float s = out_dot(sa0, sa1, wfc0, wfc1);
                if (lane < 16) ols[c * OSTRIDE + (st - 1)] = s + bfc;
            }
        }
    }

    // final output column: h_511 lives in hbuf[0] (step 511 wrote rb^1 = 0)
    if (w == 3) {
        const unsigned short* hrd = hbuf[0];
        short8 a0 = *(const short8*)(hrd + c * HSTRIDE + 8 * qq);
        short8 a1 = *(const short8*)(hrd + c * HSTRIDE + 32 + 8 * qq);
        float s = out_dot(a0, a1, wfc0, wfc1);
        if (lane < 16) ols[c * OSTRIDE + (T_STEPS - 1)] = s + bfc;
    }
    __syncthreads();

    // bulk store: LDS out -> global, coalesced (consecutive tid -> consecutive t)
    for (int i = tid; i < 16 * T_STEPS; i += 256) {
        int b = i >> 9;
        int t = i & (T_STEPS - 1);
        out[(size_t)(b0 + b) * T_STEPS + t] = ols[b * OSTRIDE + t];
    }
}

extern "C" void kernel_launch(void* const* d_in, const int* in_sizes, int n_in,
                              void* d_out, int out_size, void* d_ws, size_t ws_size,
                              hipStream_t stream) {
    const float* x    = (const float*)d_in[0];
    const float* w_ih = (const float*)d_in[1];
    const float* w_hh = (const float*)d_in[2];
    const float* b_ih = (const float*)d_in[3];
    const float* b_hh = (const float*)d_in[4];
    const float* w_fc = (const float*)d_in[5];
    const float* b_fc = (const float*)d_in[6];
    float* out = (float*)d_out;
    hipLaunchKernelGGL(lstm_kernel, dim3(128), dim3(256), 0, stream,
                       x, w_ih, w_hh, b_ih, b_hh, w_fc, b_fc, out);
}

// Round 5
// 318.552 us; speedup vs baseline: 1.2063x; 1.0788x over previous
//
#include <hip/hip_runtime.h>

#define T_STEPS 512
#define HSTRIDE 72     // shorts per LDS h-row (16B-aligned; conflict-free b128 phases)
#define XSTRIDE 520    // _Float16 per x-row
#define OSTRIDE 513    // floats per out-row
#define NB 8           // batches per block

typedef short short8 __attribute__((ext_vector_type(8)));
typedef float f32x4 __attribute__((ext_vector_type(4)));
typedef _Float16 half4 __attribute__((ext_vector_type(4)));

#define K1 1.442695041f    // log2(e)
#define K2 2.885390082f    // 2*log2(e)

__device__ __forceinline__ float ex2(float x) {
#if __has_builtin(__builtin_amdgcn_exp2f)
    return __builtin_amdgcn_exp2f(x);
#else
    return exp2f(x);
#endif
}
__device__ __forceinline__ float rcp_fast(float x) {
#if __has_builtin(__builtin_amdgcn_rcpf)
    return __builtin_amdgcn_rcpf(x);
#else
    return 1.0f / x;
#endif
}
__device__ __forceinline__ unsigned short f2bf(float f) {
    union { float f; unsigned u; } v; v.f = f;
    unsigned r = v.u + 0x7fffu + ((v.u >> 16) & 1u);   // RNE
    return (unsigned short)(r >> 16);
}
__device__ __forceinline__ float bf2f(unsigned short b) {
    union { float f; unsigned u; } v; v.u = ((unsigned)b) << 16;
    return v.f;
}

// partial fc-dot over this lane's A-fragment slice, reduced over the 4 k-quads
__device__ __forceinline__ float out_dot(short8 a0, short8 a1,
                                         const float* wfc0, const float* wfc1) {
    float s = 0.f;
#pragma unroll
    for (int j = 0; j < 8; ++j) s = fmaf(bf2f((unsigned short)a0[j]), wfc0[j], s);
#pragma unroll
    for (int j = 0; j < 8; ++j) s = fmaf(bf2f((unsigned short)a1[j]), wfc1[j], s);
    s += __shfl_xor(s, 16);
    s += __shfl_xor(s, 32);
    return s;   // full 64-dot for batch row m = lane&15, on all lanes
}

// 256 thr = 4 waves, 8 batches/block, 256 blocks (all 256 CUs).
// Wave w owns hidden units 16w..16w+15. Batches sit in MFMA rows 0-7
// (rows 8-15 of the LDS h-tile stay zero). After the MFMA, a shfl_xor(32)
// spreads rows 2-3 data to lanes 32-63 so ALL 64 lanes run activations
// (2 (batch,unit) pairs each) -> per-SIMD trans issue halves vs R4.
__global__ __launch_bounds__(256, 1) void lstm_kernel(
    const float* __restrict__ x, const float* __restrict__ w_ih,
    const float* __restrict__ w_hh, const float* __restrict__ b_ih,
    const float* __restrict__ b_hh, const float* __restrict__ w_fc,
    const float* __restrict__ b_fc, float* __restrict__ out)
{
    __shared__ __align__(16) unsigned short hbuf[2][16 * HSTRIDE];  // 4.6 KB
    __shared__ __align__(16) _Float16 xls[NB * XSTRIDE];            // 8.3 KB
    __shared__ __align__(16) float ols[NB * OSTRIDE];               // 16.4 KB

    const int tid  = threadIdx.x;
    const int w    = tid >> 6;        // wave 0..3
    const int lane = tid & 63;
    const int qq   = lane >> 4;       // 0..3 (A-frag k-quad / D row-group)
    const int c    = lane & 15;       // unit-in-tile / A-row
    const int hi   = lane >> 5;       // 0/1: activation row-half after swap
    const int q2   = qq & 1;
    const int rowbase = 4 * q2 + 2 * hi;   // this lane's 2 batch rows
    const int b0   = blockIdx.x * NB;

    // ---- stage x: global -> LDS (fp16), coalesced float4 reads ----
    for (int i = tid; i < NB * 128; i += 256) {      // 8 rows x 128 float4
        int b  = i >> 7;
        int t4 = i & 127;
        float4 v = *(const float4*)(x + (size_t)(b0 + b) * T_STEPS + t4 * 4);
        half4 hv;
        hv[0] = (_Float16)v.x; hv[1] = (_Float16)v.y;
        hv[2] = (_Float16)v.z; hv[3] = (_Float16)v.w;
        *(half4*)(&xls[b * XSTRIDE + t4 * 4]) = hv;
    }
    // zero BOTH h buffers; rows 8-15 stay zero forever (A-row padding)
    for (int i = tid; i < 2 * 16 * HSTRIDE; i += 256)
        ((unsigned short*)hbuf)[i] = 0;

    // ---- B fragments (weights) in VGPRs: tile n = gate class, K-frag kk ----
    short8 bfrag[4][2];
    float bias_n[4], wih_n[4];
#pragma unroll
    for (int n = 0; n < 4; ++n) {
        int g = 64 * n + 16 * w + c;
        bias_n[n] = b_ih[g] + b_hh[g];
        wih_n[n]  = w_ih[g];
#pragma unroll
        for (int kk = 0; kk < 2; ++kk) {
            const float* wp = w_hh + g * 64 + 32 * kk + 8 * qq;
            float4 lo = *(const float4*)(wp);
            float4 hi4 = *(const float4*)(wp + 4);
            short8 f;
            f[0] = (short)f2bf(lo.x); f[1] = (short)f2bf(lo.y);
            f[2] = (short)f2bf(lo.z); f[3] = (short)f2bf(lo.w);
            f[4] = (short)f2bf(hi4.x); f[5] = (short)f2bf(hi4.y);
            f[6] = (short)f2bf(hi4.z); f[7] = (short)f2bf(hi4.w);
            bfrag[n][kk] = f;
        }
    }

    // fc weights aligned to this lane's A-fragment k-slice
    float wfc0[8], wfc1[8];
#pragma unroll
    for (int j = 0; j < 8; ++j) { wfc0[j] = w_fc[8 * qq + j]; wfc1[j] = w_fc[32 + 8 * qq + j]; }
    const float bfc = b_fc[0];

    float cs[2] = {0.f, 0.f};   // fp32 cell state for rows rowbase+rr

    __syncthreads();

    short8 sa0 = {}, sa1 = {};  // saved A-frags for rotated fc-dot

    for (int tq = 0; tq < 128; ++tq) {
        // x for acc-init: rows 4*(qq&1)+r (valid for qq<2 lanes; qq>=2 rows discarded)
        float xq[4][4];          // [r][dt]
#pragma unroll
        for (int r = 0; r < 4; ++r) {
            half4 hx = *(const half4*)(&xls[(4 * q2 + r) * XSTRIDE + tq * 4]);
            xq[r][0] = (float)hx[0]; xq[r][1] = (float)hx[1];
            xq[r][2] = (float)hx[2]; xq[r][3] = (float)hx[3];
        }

#pragma unroll
        for (int dt = 0; dt < 4; ++dt) {
            const int t  = tq * 4 + dt;
            const int rb = t & 1;
            const unsigned short* hrd = hbuf[rb];

            // A-frags: A[m=c][k=32kk+8qq+j] of h_{t-1}; rows c>=8 are zero
            short8 a0 = *(const short8*)(hrd + c * HSTRIDE + 8 * qq);
            short8 a1 = *(const short8*)(hrd + c * HSTRIDE + 32 + 8 * qq);

            if (dt == w) { sa0 = a0; sa1 = a1; }   // rotate fc-dot ownership

            // acc init = x*w_ih + bias on rows 0-7 (C rows 8-15 = junk, discarded)
            f32x4 acc[4];
#pragma unroll
            for (int n = 0; n < 4; ++n) {
                f32x4 a;
                a[0] = fmaf(xq[0][dt], wih_n[n], bias_n[n]);
                a[1] = fmaf(xq[1][dt], wih_n[n], bias_n[n]);
                a[2] = fmaf(xq[2][dt], wih_n[n], bias_n[n]);
                a[3] = fmaf(xq[3][dt], wih_n[n], bias_n[n]);
                acc[n] = __builtin_amdgcn_mfma_f32_16x16x32_bf16(a0, bfrag[n][0], a, 0, 0, 0);
                acc[n] = __builtin_amdgcn_mfma_f32_16x16x32_bf16(a1, bfrag[n][1], acc[n], 0, 0, 0);
            }

            // spread rows 2-3 to lanes 32-63: each lane then owns 2 rows
            float v[4][2];
#pragma unroll
            for (int n = 0; n < 4; ++n) {
                float s2 = __shfl_xor(acc[n][2], 32);
                float s3 = __shfl_xor(acc[n][3], 32);
                v[n][0] = hi ? s2 : acc[n][0];
                v[n][1] = hi ? s3 : acc[n][1];
            }

            // fused activations; this lane owns (batch rowbase+rr, unit 16w+c)
            unsigned short* hwr = hbuf[rb ^ 1];
#pragma unroll
            for (int rr = 0; rr < 2; ++rr) {
                float vi = v[0][rr], vf = v[1][rr], vg = v[2][rr], vo = v[3][rr];
                float A  = ex2(vi * -K1);
                float B  = ex2(vg *  K2);
                float ig = (B - 1.0f) * rcp_fast((1.0f + A) * (1.0f + B));
                float rf = rcp_fast(1.0f + ex2(vf * -K1));
                cs[rr] = fmaf(cs[rr], rf, ig);
                float cc = fminf(fmaxf(cs[rr], -15.f), 15.f);
                float Ao = ex2(vo * -K1);
                float C  = ex2(cc *  K2);
                float h  = (C - 1.0f) * rcp_fast((1.0f + Ao) * (1.0f + C));
                hwr[(rowbase + rr) * HSTRIDE + 16 * w + c] = f2bf(h);
            }
            __syncthreads();
        }

        // rotated fc-dot: saved frag is A of step st = tq*4+w = h_{st-1}
        {
            int st = tq * 4 + w;
            if (st > 0) {
                float s = out_dot(sa0, sa1, wfc0, wfc1);
                if (lane < NB) ols[c * OSTRIDE + (st - 1)] = s + bfc;
            }
        }
    }

    // final output column: h_511 lives in hbuf[0]
    if (w == 3) {
        const unsigned short* hrd = hbuf[0];
        short8 a0 = *(const short8*)(hrd + c * HSTRIDE + 8 * qq);
        short8 a1 = *(const short8*)(hrd + c * HSTRIDE + 32 + 8 * qq);
        float s = out_dot(a0, a1, wfc0, wfc1);
        if (lane < NB) ols[c * OSTRIDE + (T_STEPS - 1)] = s + bfc;
    }
    __syncthreads();

    // bulk store: LDS out -> global, coalesced
    for (int i = tid; i < NB * T_STEPS; i += 256) {
        int b = i >> 9;
        int t = i & (T_STEPS - 1);
        out[(size_t)(b0 + b) * T_STEPS + t] = ols[b * OSTRIDE + t];
    }
}

extern "C" void kernel_launch(void* const* d_in, const int* in_sizes, int n_in,
                              void* d_out, int out_size, void* d_ws, size_t ws_size,
                              hipStream_t stream) {
    const float* x    = (const float*)d_in[0];
    const float* w_ih = (const float*)d_in[1];
    const float* w_hh = (const float*)d_in[2];
    const float* b_ih = (const float*)d_in[3];
    const float* b_hh = (const float*)d_in[4];
    const float* w_fc = (const float*)d_in[5];
    const float* b_fc = (const float*)d_in[6];
    float* out = (float*)d_out;
    hipLaunchKernelGGL(lstm_kernel, dim3(2048 / NB), dim3(256), 0, stream,
                       x, w_ih, w_hh, b_ih, b_hh, w_fc, b_fc, out);
}